// Round 6
// baseline (170.683 us; speedup 1.0000x reference)
//
#include <hip/hip_runtime.h>

#define DM 128

typedef __attribute__((ext_vector_type(8))) __bf16 bf16x8;
typedef __attribute__((ext_vector_type(4))) float f32x4;

__device__ inline unsigned short f2bf(float f) {
    unsigned u = __float_as_uint(f);
    u += 0x7FFFu + ((u >> 16) & 1u);
    return (unsigned short)(u >> 16);
}

// ---------- prep: weights->bf16 (blocks 0..63) + offset scan (64) + X->bf16 (65..) ----------
__global__ void prep(const int* __restrict__ agents, int B, int M,
                     const float* __restrict__ wqkv, const float* __restrict__ wout,
                     const float* __restrict__ x,
                     int* __restrict__ offs,
                     unsigned short* __restrict__ wqkv_bf,
                     unsigned short* __restrict__ wout_bf,
                     unsigned short* __restrict__ xbf) {
    if (blockIdx.x < 64) {
        int idx = (blockIdx.x * 256 + threadIdx.x) * 4;   // 0..65532
        if (idx < 49152) {
            float4 v = *(const float4*)(wqkv + idx);
            ushort4 o;
            o.x = f2bf(v.x); o.y = f2bf(v.y); o.z = f2bf(v.z); o.w = f2bf(v.w);
            *(ushort4*)(wqkv_bf + idx) = o;
        } else {
            int j = idx - 49152;
            float4 v = *(const float4*)(wout + j);
            ushort4 o;
            o.x = f2bf(v.x); o.y = f2bf(v.y); o.z = f2bf(v.z); o.w = f2bf(v.w);
            *(ushort4*)(wout_bf + j) = o;
        }
    } else if (blockIdx.x == 64) {
        __shared__ int part[256];
        const int tid = threadIdx.x;
        const int per = (B + 255) >> 8;
        const int base = tid * per;
        int s = 0;
        for (int i = 0; i < per; ++i) {
            int idx = base + i;
            if (idx < B) s += agents[idx];
        }
        part[tid] = s;
        __syncthreads();
        for (int off = 1; off < 256; off <<= 1) {
            int v = (tid >= off) ? part[tid - off] : 0;
            __syncthreads();
            part[tid] += v;
            __syncthreads();
        }
        int run = (tid == 0) ? 0 : part[tid - 1];
        for (int i = 0; i < per; ++i) {
            int idx = base + i;
            if (idx < B) { offs[idx] = run; run += agents[idx]; }
        }
    } else {
        // X fp32 -> bf16, grid-strided (BW-bound, ~51MB)
        const int nf4 = M * 32;
        const int stride = ((int)gridDim.x - 65) * 256;
        for (int idx = ((int)blockIdx.x - 65) * 256 + (int)threadIdx.x; idx < nf4;
             idx += stride) {
            float4 v = ((const float4*)x)[idx];
            ushort4 o;
            o.x = f2bf(v.x); o.y = f2bf(v.y); o.z = f2bf(v.z); o.w = f2bf(v.w);
            ((ushort4*)xbf)[idx] = o;
        }
    }
}

// ---------- phase 1: QKV GEMM + attention, one WAVE per (sample, head) ----------
// 512 threads = 8 waves = the 8 heads of one sample. Zero LDS. One barrier (xbf/obuf alias).
// X frags: xf[ks] = xbf[row=base+t*16+l16][ks*32+quad*8]  (identical A/B-frag gather).
// Q/K: mfma(wf, xf) -> lane=token, (quad,r)=col; rebuilt to operand layout by 4 shfls (r5-verified).
// V:   mfma(xf, wfv) -> (quad,r)=token t*16+quad*4+r, lane=v-col h*16+l16
//      == vA[t>>1][(t&1)*4+r] DIRECTLY (the PV pi-slot layout). No LDS, no shuffle.
// Attention: swapped QK^T mfma(kf,qf); softmax per lane + 2 shuffles; PV mfma(vA,pf) (r5-verified).
// Rows beyond n (next sample's data / O-overwritten, finite garbage) masked by thr & row<n.
template<int NT>
__device__ __forceinline__ void qa_body(
    const unsigned short* __restrict__ xbf,
    const unsigned short* __restrict__ wqkvb,
    const float* __restrict__ bqkv,
    unsigned short* __restrict__ obuf,
    int n, int base, int M, int h, int quad, int l16)
{
    constexpr int G   = (NT + 1) / 2;   // 32-key PV groups
    constexpr int KT2 = 2 * G;          // padded 16-key tile count
    bf16x8 qf[NT], kf[NT], vA[G];
    #pragma unroll
    for (int g = 0; g < G; ++g) vA[g] = (bf16x8)(__bf16)0.0f;   // odd-NT upper half stays 0

    const int shA = (quad & 1) * 32 + l16;   // shfl sources for Q/K frag rebuild
    const int shB = shA + 16;

    // ---- Q and K segments: mfma(wf, xf) + 4-shfl rebuild ----
    #pragma unroll
    for (int seg = 0; seg < 2; ++seg) {
        bf16x8 wf[4];
        #pragma unroll
        for (int ks = 0; ks < 4; ++ks)
            wf[ks] = *(const bf16x8*)(wqkvb +
                     (size_t)(seg * 128 + h * 16 + l16) * 128 + ks * 32 + quad * 8);
        const float4 bs = *(const float4*)(bqkv + seg * 128 + h * 16 + quad * 4);
        #pragma unroll
        for (int mt = 0; mt < NT; ++mt) {
            int row = base + mt * 16 + l16;
            row = row < M ? row : M - 1;
            const unsigned short* xr = xbf + (size_t)row * 128;
            f32x4 acc = {0.f, 0.f, 0.f, 0.f};
            #pragma unroll
            for (int ks = 0; ks < 4; ++ks) {
                bf16x8 xf = *(const bf16x8*)(xr + ks * 32 + quad * 8);
                acc = __builtin_amdgcn_mfma_f32_16x16x32_bf16(wf[ks], xf, acc, 0, 0, 0);
            }
            ushort4 w;
            w.x = f2bf(acc[0] + bs.x); w.y = f2bf(acc[1] + bs.y);
            w.z = f2bf(acc[2] + bs.z); w.w = f2bf(acc[3] + bs.w);
            unsigned u0 = (unsigned)w.x | ((unsigned)w.y << 16);
            unsigned u1 = (unsigned)w.z | ((unsigned)w.w << 16);
            uint4 q;
            q.x = __shfl(u0, shA); q.y = __shfl(u1, shA);
            q.z = __shfl(u0, shB); q.w = __shfl(u1, shB);
            bf16x8 fr = (quad < 2) ? __builtin_bit_cast(bf16x8, q)
                                   : (bf16x8)(__bf16)0.0f;
            if (seg == 0) qf[mt] = fr; else kf[mt] = fr;
        }
    }
    // ---- V segment: swapped operands -> vA layout directly ----
    {
        bf16x8 wfv[4];
        #pragma unroll
        for (int ks = 0; ks < 4; ++ks)
            wfv[ks] = *(const bf16x8*)(wqkvb +
                      (size_t)(256 + h * 16 + l16) * 128 + ks * 32 + quad * 8);
        const float bv = bqkv[256 + h * 16 + l16];
        #pragma unroll
        for (int t = 0; t < NT; ++t) {
            int row = base + t * 16 + l16;
            row = row < M ? row : M - 1;
            const unsigned short* xr = xbf + (size_t)row * 128;
            f32x4 acc = {0.f, 0.f, 0.f, 0.f};
            #pragma unroll
            for (int ks = 0; ks < 4; ++ks) {
                bf16x8 xf = *(const bf16x8*)(xr + ks * 32 + quad * 8);
                acc = __builtin_amdgcn_mfma_f32_16x16x32_bf16(xf, wfv[ks], acc, 0, 0, 0);
            }
            #pragma unroll
            for (int r = 0; r < 4; ++r)
                vA[t >> 1][(t & 1) * 4 + r] = (__bf16)(acc[r] + bv);
        }
    }

    // all xbf reads done; block's O stores may now overwrite these rows (obuf == xbf region)
    __syncthreads();

    int thr[KT2];      // key kt*16+quad*4+r valid iff r < thr[kt]
    #pragma unroll
    for (int kt = 0; kt < KT2; ++kt) {
        int t = n - kt * 16 - quad * 4;
        thr[kt] = t < 0 ? 0 : (t > 4 ? 4 : t);
    }
    const float SC2 = 0.25f * 1.44269504088896340736f;   // 1/sqrt(16), log2 domain

    #pragma unroll
    for (int mt = 0; mt < NT; ++mt) {
        float pr[KT2][4];
        float mm = -3.0e38f;   // max over all (incl. finite garbage) keys: exact in softmax
        #pragma unroll
        for (int kt = 0; kt < KT2; ++kt) {
            if (kt < NT) {
                f32x4 sc = __builtin_amdgcn_mfma_f32_16x16x32_bf16(
                    kf[kt], qf[mt], (f32x4){0.f, 0.f, 0.f, 0.f}, 0, 0, 0);
                #pragma unroll
                for (int r = 0; r < 4; ++r) {
                    float v = sc[r] * SC2;
                    pr[kt][r] = v;
                    mm = fmaxf(mm, v);
                }
            } else {
                #pragma unroll
                for (int r = 0; r < 4; ++r) pr[kt][r] = -3.0e38f;
            }
        }
        mm = fmaxf(mm, __shfl_xor(mm, 16));
        mm = fmaxf(mm, __shfl_xor(mm, 32));
        float ll = 0.f;
        #pragma unroll
        for (int kt = 0; kt < KT2; ++kt)
            #pragma unroll
            for (int r = 0; r < 4; ++r) {
                float e = exp2f(pr[kt][r] - mm);
                e = (r < thr[kt]) ? e : 0.f;
                pr[kt][r] = e;
                ll += e;
            }
        ll += __shfl_xor(ll, 16);
        ll += __shfl_xor(ll, 32);
        float inv = __builtin_amdgcn_rcpf(ll);
        bf16x8 pf[G];
        #pragma unroll
        for (int g = 0; g < G; ++g)
            #pragma unroll
            for (int j = 0; j < 8; ++j)
                pf[g][j] = (__bf16)(pr[2 * g + (j >> 2)][j & 3] * inv);
        f32x4 o = __builtin_amdgcn_mfma_f32_16x16x32_bf16(
            vA[0], pf[0], (f32x4){0.f, 0.f, 0.f, 0.f}, 0, 0, 0);
        if constexpr (G == 2)
            o = __builtin_amdgcn_mfma_f32_16x16x32_bf16(vA[1], pf[1], o, 0, 0, 0);
        const int row = mt * 16 + l16;
        if (row < n) {   // O[q=row][d=h*16+quad*4+r] -> one 8B store
            ushort4 w;
            w.x = f2bf(o[0]); w.y = f2bf(o[1]); w.z = f2bf(o[2]); w.w = f2bf(o[3]);
            *(ushort4*)(obuf + (size_t)(base + row) * 128 + h * 16 + quad * 4) = w;
        }
    }
}

__launch_bounds__(512, 2)
__global__ void qkvattn(const unsigned short* __restrict__ xbf,
                        const unsigned short* __restrict__ wqkvb,
                        const float* __restrict__ bqkv,
                        unsigned short* __restrict__ obuf,
                        const int* __restrict__ agents,
                        const int* __restrict__ offs,
                        int M) {
    const int s = blockIdx.x;
    const int n = agents[s];
    const int base = offs[s];
    const int tid = threadIdx.x;
    const int h = tid >> 6, quad = (tid >> 4) & 3, l16 = tid & 15;
    const int nt = (n + 15) >> 4;   // block-uniform -> the internal barrier is safe
    if      (nt == 1) qa_body<1>(xbf, wqkvb, bqkv, obuf, n, base, M, h, quad, l16);
    else if (nt == 2) qa_body<2>(xbf, wqkvb, bqkv, obuf, n, base, M, h, quad, l16);
    else if (nt == 3) qa_body<3>(xbf, wqkvb, bqkv, obuf, n, base, M, h, quad, l16);
    else              qa_body<4>(xbf, wqkvb, bqkv, obuf, n, base, M, h, quad, l16);
}

// ---------- kernel 3: out-proj GEMM (r3-verified, unchanged) ----------
__launch_bounds__(256, 4)
__global__ void oproj(const unsigned short* __restrict__ attn_b,  // [M][128] bf16 (ws)
                      const unsigned short* __restrict__ woutb,
                      const float* __restrict__ bout,
                      float* __restrict__ out, int M) {
    __shared__ __align__(16) unsigned short Ws[128 * 136];   // 34816 B
    __shared__ __align__(16) float biass[128];
    const int m0 = blockIdx.x * 64;
    const int tid = threadIdx.x;

    for (int f = tid; f < 2048; f += 256) {
        int t = f >> 4, c = f & 15;
        *(uint4*)&Ws[t * 136 + c * 8] = *(const uint4*)(woutb + (size_t)t * 128 + c * 8);
    }
    if (tid < 32)
        ((float4*)biass)[tid] = ((const float4*)bout)[tid];
    __syncthreads();                                  // the ONLY barrier

    const int wave = tid >> 6, lane = tid & 63, quad = lane >> 4, l16 = lane & 15;
    const int mw = m0 + wave * 16;                   // each wave: 16 rows

    bf16x8 af[4];
    {
        int row = mw + l16;
        row = (row < M) ? row : (M - 1);
        #pragma unroll
        for (int ks = 0; ks < 4; ++ks)
            af[ks] = *(const bf16x8*)(attn_b + (size_t)row * DM + ks * 32 + quad * 8);
    }

    const int row0 = mw + l16;

    for (int ct = 0; ct < 8; ++ct) {
        bf16x8 bc[4];
        #pragma unroll
        for (int ks = 0; ks < 4; ++ks)
            bc[ks] = *(const bf16x8*)&Ws[(ct * 16 + l16) * 136 + ks * 32 + quad * 8];
        f32x4 a0 = {0.f, 0.f, 0.f, 0.f};
        #pragma unroll
        for (int ks = 0; ks < 4; ++ks)
            a0 = __builtin_amdgcn_mfma_f32_16x16x32_bf16(bc[ks], af[ks], a0, 0, 0, 0);
        const int n0 = ct * 16 + quad * 4;
        const float4 b4 = *(const float4*)(biass + n0);
        float4 o0;
        o0.x = a0[0] + b4.x; o0.y = a0[1] + b4.y; o0.z = a0[2] + b4.z; o0.w = a0[3] + b4.w;
        if (row0 < M) *(float4*)(out + (size_t)row0 * DM + n0) = o0;
    }
}

extern "C" void kernel_launch(void* const* d_in, const int* in_sizes, int n_in,
                              void* d_out, int out_size, void* d_ws, size_t ws_size,
                              hipStream_t stream) {
    const float* att_in     = (const float*)d_in[0];
    const float* in_proj_w  = (const float*)d_in[1];
    const float* in_proj_b  = (const float*)d_in[2];
    const float* out_proj_w = (const float*)d_in[3];
    const float* out_proj_b = (const float*)d_in[4];
    const int*   agents     = (const int*)d_in[5];
    const int B = in_sizes[5];
    const int M = out_size / DM;             // total tokens (66560)

    // ws layout (~17.2 MB):
    //   [0,8192)         offs
    //   [8192,106496)    wqkv bf16
    //   [106496,139264)  wout bf16
    //   [139264,+M*256)  X bf16 (phase 1 input), overwritten in place by O bf16
    int* offs = (int*)d_ws;
    unsigned short* wqkv_bf = (unsigned short*)((char*)d_ws + 8192);
    unsigned short* wout_bf = (unsigned short*)((char*)d_ws + 106496);
    unsigned short* xobuf   = (unsigned short*)((char*)d_ws + 139264);

    hipLaunchKernelGGL(prep, dim3(65 + 1024), dim3(256), 0, stream,
                       agents, B, M, in_proj_w, out_proj_w, att_in,
                       offs, wqkv_bf, wout_bf, xobuf);
    hipLaunchKernelGGL(qkvattn, dim3(B), dim3(512), 0, stream,
                       xobuf, wqkv_bf, in_proj_b, xobuf, agents, offs, M);
    hipLaunchKernelGGL(oproj, dim3((M + 63) / 64), dim3(256), 0, stream,
                       xobuf, wout_bf, out_proj_b, (float*)d_out, M);
}

// Round 7
// 153.207 us; speedup vs baseline: 1.1141x; 1.1141x over previous
//
#include <hip/hip_runtime.h>

#define DM 128

typedef __attribute__((ext_vector_type(8))) __bf16 bf16x8;
typedef __attribute__((ext_vector_type(4))) float f32x4;

__device__ inline unsigned short f2bf(float f) {
    unsigned u = __float_as_uint(f);
    u += 0x7FFFu + ((u >> 16) & 1u);
    return (unsigned short)(u >> 16);
}

// ---------- prep: weights->bf16 (blocks 0..63) + offset scan (64) + X->bf16 (65..) ----------
__global__ void prep(const int* __restrict__ agents, int B, int M,
                     const float* __restrict__ wqkv, const float* __restrict__ wout,
                     const float* __restrict__ x,
                     int* __restrict__ offs,
                     unsigned short* __restrict__ wqkv_bf,
                     unsigned short* __restrict__ wout_bf,
                     unsigned short* __restrict__ xbf) {
    if (blockIdx.x < 64) {
        int idx = (blockIdx.x * 256 + threadIdx.x) * 4;   // 0..65532
        if (idx < 49152) {
            float4 v = *(const float4*)(wqkv + idx);
            ushort4 o;
            o.x = f2bf(v.x); o.y = f2bf(v.y); o.z = f2bf(v.z); o.w = f2bf(v.w);
            *(ushort4*)(wqkv_bf + idx) = o;
        } else {
            int j = idx - 49152;
            float4 v = *(const float4*)(wout + j);
            ushort4 o;
            o.x = f2bf(v.x); o.y = f2bf(v.y); o.z = f2bf(v.z); o.w = f2bf(v.w);
            *(ushort4*)(wout_bf + j) = o;
        }
    } else if (blockIdx.x == 64) {
        __shared__ int part[256];
        const int tid = threadIdx.x;
        const int per = (B + 255) >> 8;
        const int base = tid * per;
        int s = 0;
        for (int i = 0; i < per; ++i) {
            int idx = base + i;
            if (idx < B) s += agents[idx];
        }
        part[tid] = s;
        __syncthreads();
        for (int off = 1; off < 256; off <<= 1) {
            int v = (tid >= off) ? part[tid - off] : 0;
            __syncthreads();
            part[tid] += v;
            __syncthreads();
        }
        int run = (tid == 0) ? 0 : part[tid - 1];
        for (int i = 0; i < per; ++i) {
            int idx = base + i;
            if (idx < B) { offs[idx] = run; run += agents[idx]; }
        }
    } else {
        // X fp32 -> bf16, grid-strided (BW-bound, ~77MB traffic)
        const int nf4 = M * 32;
        const int stride = ((int)gridDim.x - 65) * 256;
        for (int idx = ((int)blockIdx.x - 65) * 256 + (int)threadIdx.x; idx < nf4;
             idx += stride) {
            float4 v = ((const float4*)x)[idx];
            ushort4 o;
            o.x = f2bf(v.x); o.y = f2bf(v.y); o.z = f2bf(v.z); o.w = f2bf(v.w);
            ((ushort4*)xbf)[idx] = o;
        }
    }
}

// ---------- phase 1: QKV GEMM + attention. ONE 64-thread block per (sample, head). ----------
// Zero LDS, zero barriers (O goes to a non-aliasing buffer: d_out's [M][256] bf16 slots).
// Per 16-row tile: xf[4] loaded ONCE, consumed by THREE independent MFMA chains (Q,K,V):
//   Q/K: mfma(wf, xf)  -> lane=token, (quad,r)=col; rebuilt to operand layout by 4 shfls.
//   V:   mfma(xf, wfv) -> (quad,r)=token t*16+quad*4+r, lane=vcol == vA[t>>1][(t&1)*4+r]
//        directly (the PV pi-slot layout). No LDS, no shuffle.          [r5/r6-verified]
// Attention: swapped QK^T mfma(kf,qf); per-lane softmax + 2 shuffles; PV mfma(vA,pf).
// Rows beyond n (neighbor samples' X, finite) are masked by thr / row<n. [r4-r6-verified]
template<int NT>
__device__ __forceinline__ void qa_body(
    const unsigned short* __restrict__ xbf,
    const unsigned short* __restrict__ wqkvb,
    const float* __restrict__ bqkv,
    unsigned short* __restrict__ obuf,     // [M][256] bf16 slots (d_out)
    int n, int base, int M, int h, int quad, int l16)
{
    constexpr int G   = (NT + 1) / 2;   // 32-key PV groups
    constexpr int KT2 = 2 * G;          // padded 16-key tile count
    bf16x8 qf[NT], kf[NT], vA[G];
    #pragma unroll
    for (int g = 0; g < G; ++g) vA[g] = (bf16x8)(__bf16)0.0f;   // odd-NT upper half stays 0

    // hoisted weight fragments (loop-invariant; L2-hot, shared by all 16384 blocks)
    bf16x8 wfq[4], wfk[4], wfv[4];
    const unsigned short* wq = wqkvb + (size_t)(h * 16 + l16) * 128;
    #pragma unroll
    for (int ks = 0; ks < 4; ++ks) {
        wfq[ks] = *(const bf16x8*)(wq + ks * 32 + quad * 8);
        wfk[ks] = *(const bf16x8*)(wq + 128 * 128 + ks * 32 + quad * 8);
        wfv[ks] = *(const bf16x8*)(wq + 256 * 128 + ks * 32 + quad * 8);
    }
    const float4 bq4 = *(const float4*)(bqkv + h * 16 + quad * 4);
    const float4 bk4 = *(const float4*)(bqkv + 128 + h * 16 + quad * 4);
    const float  bv  = bqkv[256 + h * 16 + l16];

    const int shA = (quad & 1) * 32 + l16;   // shfl sources for Q/K frag rebuild
    const int shB = shA + 16;

    #pragma unroll
    for (int mt = 0; mt < NT; ++mt) {
        int row = base + mt * 16 + l16;
        row = row < M ? row : M - 1;
        const unsigned short* xr = xbf + (size_t)row * 128;
        bf16x8 xf[4];
        #pragma unroll
        for (int ks = 0; ks < 4; ++ks)
            xf[ks] = *(const bf16x8*)(xr + ks * 32 + quad * 8);
        f32x4 qa = {0.f,0.f,0.f,0.f}, ka = {0.f,0.f,0.f,0.f}, va = {0.f,0.f,0.f,0.f};
        #pragma unroll
        for (int ks = 0; ks < 4; ++ks) {    // 3 independent MFMA chains per xf load
            qa = __builtin_amdgcn_mfma_f32_16x16x32_bf16(wfq[ks], xf[ks], qa, 0, 0, 0);
            ka = __builtin_amdgcn_mfma_f32_16x16x32_bf16(wfk[ks], xf[ks], ka, 0, 0, 0);
            va = __builtin_amdgcn_mfma_f32_16x16x32_bf16(xf[ks], wfv[ks], va, 0, 0, 0);
        }
        {   // Q rebuild: D(lane=token, regs=4 cols) -> operand frag via 4 shfls
            ushort4 w;
            w.x = f2bf(qa[0] + bq4.x); w.y = f2bf(qa[1] + bq4.y);
            w.z = f2bf(qa[2] + bq4.z); w.w = f2bf(qa[3] + bq4.w);
            unsigned u0 = (unsigned)w.x | ((unsigned)w.y << 16);
            unsigned u1 = (unsigned)w.z | ((unsigned)w.w << 16);
            uint4 q;
            q.x = __shfl(u0, shA); q.y = __shfl(u1, shA);
            q.z = __shfl(u0, shB); q.w = __shfl(u1, shB);
            qf[mt] = (quad < 2) ? __builtin_bit_cast(bf16x8, q) : (bf16x8)(__bf16)0.0f;
        }
        {   // K rebuild
            ushort4 w;
            w.x = f2bf(ka[0] + bk4.x); w.y = f2bf(ka[1] + bk4.y);
            w.z = f2bf(ka[2] + bk4.z); w.w = f2bf(ka[3] + bk4.w);
            unsigned u0 = (unsigned)w.x | ((unsigned)w.y << 16);
            unsigned u1 = (unsigned)w.z | ((unsigned)w.w << 16);
            uint4 q;
            q.x = __shfl(u0, shA); q.y = __shfl(u1, shA);
            q.z = __shfl(u0, shB); q.w = __shfl(u1, shB);
            kf[mt] = (quad < 2) ? __builtin_bit_cast(bf16x8, q) : (bf16x8)(__bf16)0.0f;
        }
        #pragma unroll
        for (int r = 0; r < 4; ++r)        // V: already in pi-slot layout
            vA[mt >> 1][(mt & 1) * 4 + r] = (__bf16)(va[r] + bv);
    }

    int thr[KT2];      // key kt*16+quad*4+r valid iff r < thr[kt]
    #pragma unroll
    for (int kt = 0; kt < KT2; ++kt) {
        int t = n - kt * 16 - quad * 4;
        thr[kt] = t < 0 ? 0 : (t > 4 ? 4 : t);
    }
    const float SC2 = 0.25f * 1.44269504088896340736f;   // 1/sqrt(16), log2 domain

    #pragma unroll
    for (int mt = 0; mt < NT; ++mt) {
        float pr[KT2][4];
        float mm = -3.0e38f;   // max over all (incl. finite garbage) keys: cancels in softmax
        #pragma unroll
        for (int kt = 0; kt < KT2; ++kt) {
            if (kt < NT) {
                f32x4 sc = __builtin_amdgcn_mfma_f32_16x16x32_bf16(
                    kf[kt], qf[mt], (f32x4){0.f, 0.f, 0.f, 0.f}, 0, 0, 0);
                #pragma unroll
                for (int r = 0; r < 4; ++r) {
                    float v = sc[r] * SC2;
                    pr[kt][r] = v;
                    mm = fmaxf(mm, v);
                }
            } else {
                #pragma unroll
                for (int r = 0; r < 4; ++r) pr[kt][r] = -3.0e38f;
            }
        }
        mm = fmaxf(mm, __shfl_xor(mm, 16));
        mm = fmaxf(mm, __shfl_xor(mm, 32));
        float ll = 0.f;
        #pragma unroll
        for (int kt = 0; kt < KT2; ++kt)
            #pragma unroll
            for (int r = 0; r < 4; ++r) {
                float e = exp2f(pr[kt][r] - mm);
                e = (r < thr[kt]) ? e : 0.f;
                pr[kt][r] = e;
                ll += e;
            }
        ll += __shfl_xor(ll, 16);
        ll += __shfl_xor(ll, 32);
        float inv = __builtin_amdgcn_rcpf(ll);
        bf16x8 pf[G];
        #pragma unroll
        for (int g = 0; g < G; ++g)
            #pragma unroll
            for (int j = 0; j < 8; ++j)
                pf[g][j] = (__bf16)(pr[2 * g + (j >> 2)][j & 3] * inv);
        f32x4 o = __builtin_amdgcn_mfma_f32_16x16x32_bf16(
            vA[0], pf[0], (f32x4){0.f, 0.f, 0.f, 0.f}, 0, 0, 0);
        if constexpr (G == 2)
            o = __builtin_amdgcn_mfma_f32_16x16x32_bf16(vA[1], pf[1], o, 0, 0, 0);
        const int row = mt * 16 + l16;
        if (row < n) {   // O[q=row][d=h*16+quad*4+r] -> one 8B store into the 256-slot row
            ushort4 w;
            w.x = f2bf(o[0]); w.y = f2bf(o[1]); w.z = f2bf(o[2]); w.w = f2bf(o[3]);
            *(ushort4*)(obuf + (size_t)(base + row) * 256 + h * 16 + quad * 4) = w;
        }
    }
}

__launch_bounds__(64, 3)
__global__ void qkvattn(const unsigned short* __restrict__ xbf,
                        const unsigned short* __restrict__ wqkvb,
                        const float* __restrict__ bqkv,
                        unsigned short* __restrict__ obuf,
                        const int* __restrict__ agents,
                        const int* __restrict__ offs,
                        int M) {
    const int bid = blockIdx.x;
    const int s = bid >> 3, h = bid & 7;   // one wave per (sample, head)
    const int n = agents[s];
    const int base = offs[s];
    const int lane = threadIdx.x & 63, quad = lane >> 4, l16 = lane & 15;
    const int nt = (n + 15) >> 4;
    if      (nt == 1) qa_body<1>(xbf, wqkvb, bqkv, obuf, n, base, M, h, quad, l16);
    else if (nt == 2) qa_body<2>(xbf, wqkvb, bqkv, obuf, n, base, M, h, quad, l16);
    else if (nt == 3) qa_body<3>(xbf, wqkvb, bqkv, obuf, n, base, M, h, quad, l16);
    else              qa_body<4>(xbf, wqkvb, bqkv, obuf, n, base, M, h, quad, l16);
}

// ---------- phase 2: out-proj GEMM (r3-verified structure; O read from d_out's bf16 slots,
// fp32 result written IN PLACE: each wave reads rows [mw,mw+16) bytes [512r,512r+256) into
// registers, then writes [512r,512r+512) -- reads precede writes per wave, rows disjoint
// across waves/blocks -> race-free in-place expansion). ----------
__launch_bounds__(256, 4)
__global__ void oproj(const unsigned short* __restrict__ attn_b,  // [M][256] bf16 slots (d_out)
                      const unsigned short* __restrict__ woutb,
                      const float* __restrict__ bout,
                      float* __restrict__ out, int M) {
    __shared__ __align__(16) unsigned short Ws[128 * 136];   // 34816 B
    __shared__ __align__(16) float biass[128];
    const int m0 = blockIdx.x * 64;
    const int tid = threadIdx.x;

    for (int f = tid; f < 2048; f += 256) {
        int t = f >> 4, c = f & 15;
        *(uint4*)&Ws[t * 136 + c * 8] = *(const uint4*)(woutb + (size_t)t * 128 + c * 8);
    }
    if (tid < 32)
        ((float4*)biass)[tid] = ((const float4*)bout)[tid];
    __syncthreads();                                  // the ONLY barrier

    const int wave = tid >> 6, lane = tid & 63, quad = lane >> 4, l16 = lane & 15;
    const int mw = m0 + wave * 16;                   // each wave: 16 rows

    bf16x8 af[4];
    {
        int row = mw + l16;
        row = (row < M) ? row : (M - 1);
        #pragma unroll
        for (int ks = 0; ks < 4; ++ks)
            af[ks] = *(const bf16x8*)(attn_b + (size_t)row * 256 + ks * 32 + quad * 8);
    }

    const int row0 = mw + l16;

    for (int ct = 0; ct < 8; ++ct) {
        bf16x8 bc[4];
        #pragma unroll
        for (int ks = 0; ks < 4; ++ks)
            bc[ks] = *(const bf16x8*)&Ws[(ct * 16 + l16) * 136 + ks * 32 + quad * 8];
        f32x4 a0 = {0.f, 0.f, 0.f, 0.f};
        #pragma unroll
        for (int ks = 0; ks < 4; ++ks)
            a0 = __builtin_amdgcn_mfma_f32_16x16x32_bf16(bc[ks], af[ks], a0, 0, 0, 0);
        const int n0 = ct * 16 + quad * 4;
        const float4 b4 = *(const float4*)(biass + n0);
        float4 o0;
        o0.x = a0[0] + b4.x; o0.y = a0[1] + b4.y; o0.z = a0[2] + b4.z; o0.w = a0[3] + b4.w;
        if (row0 < M) *(float4*)(out + (size_t)row0 * DM + n0) = o0;
    }
}

extern "C" void kernel_launch(void* const* d_in, const int* in_sizes, int n_in,
                              void* d_out, int out_size, void* d_ws, size_t ws_size,
                              hipStream_t stream) {
    const float* att_in     = (const float*)d_in[0];
    const float* in_proj_w  = (const float*)d_in[1];
    const float* in_proj_b  = (const float*)d_in[2];
    const float* out_proj_w = (const float*)d_in[3];
    const float* out_proj_b = (const float*)d_in[4];
    const int*   agents     = (const int*)d_in[5];
    const int B = in_sizes[5];
    const int M = out_size / DM;             // total tokens (66560)

    // ws layout (~17.2 MB):
    //   [0,8192)         offs
    //   [8192,106496)    wqkv bf16
    //   [106496,139264)  wout bf16
    //   [139264,+M*256)  X bf16 (read-only in phase 1)
    // O bf16 lives in d_out's [M][256] slots (34MB == out_size), expanded in place by oproj.
    int* offs = (int*)d_ws;
    unsigned short* wqkv_bf = (unsigned short*)((char*)d_ws + 8192);
    unsigned short* wout_bf = (unsigned short*)((char*)d_ws + 106496);
    unsigned short* xbf     = (unsigned short*)((char*)d_ws + 139264);
    unsigned short* obuf    = (unsigned short*)d_out;

    hipLaunchKernelGGL(prep, dim3(65 + 1024), dim3(256), 0, stream,
                       agents, B, M, in_proj_w, out_proj_w, att_in,
                       offs, wqkv_bf, wout_bf, xbf);
    hipLaunchKernelGGL(qkvattn, dim3(B * 8), dim3(64), 0, stream,
                       xbf, wqkv_bf, in_proj_b, obuf, agents, offs, M);
    hipLaunchKernelGGL(oproj, dim3((M + 63) / 64), dim3(256), 0, stream,
                       obuf, wout_bf, out_proj_b, (float*)d_out, M);
}